// Round 6
// baseline (230.531 us; speedup 1.0000x reference)
//
#include <hip/hip_runtime.h>

// Problem constants
#define B 8
#define S 4096
#define H 32
#define D 128
#define DM 4096   // H*D

#define SPLIT 4               // s-chunks per (b, head-quad)
#define NR (S / SPLIT)        // 1024 rows per block
#define HQ 4                  // heads per block (2 KB contiguous per row)
#define NHQ (H / HQ)          // 8 head-quads
#define NT 1024
#define WAVES 16
#define RPW (NR / WAVES)      // 64 consecutive rows per wave
#define PSTR 132              // partial record: 128 O + m + l (+pad)

typedef float v4f __attribute__((ext_vector_type(4)));

// ---------------------------------------------------------------------------
// Kernel 1: q = hidden @ Wq^T + bq  (proven round-1 structure).
// ---------------------------------------------------------------------------
__global__ __launch_bounds__(256) void qproj_kernel(
    const float* __restrict__ hidden, const float* __restrict__ Wq,
    const float* __restrict__ bq, float* __restrict__ qout)
{
    const int lane = threadIdx.x & 63;
    const int wave = threadIdx.x >> 6;
    const int j0 = (blockIdx.x * 4 + wave) * 2;
    const int j1 = j0 + 1;

    const v4f* __restrict__ w0 = (const v4f*)(Wq + (size_t)j0 * DM);
    const v4f* __restrict__ w1 = (const v4f*)(Wq + (size_t)j1 * DM);
    const v4f* __restrict__ hid = (const v4f*)hidden;

    float a0[B], a1[B];
#pragma unroll
    for (int b = 0; b < B; ++b) { a0[b] = 0.f; a1[b] = 0.f; }

#pragma unroll 4
    for (int i = 0; i < DM / (4 * 64); ++i) {   // 16 iterations
        const int idx = lane + 64 * i;
        const v4f wv0 = __builtin_nontemporal_load(w0 + idx);
        const v4f wv1 = __builtin_nontemporal_load(w1 + idx);
#pragma unroll
        for (int b = 0; b < B; ++b) {
            const v4f hv = hid[b * (DM / 4) + idx];
            a0[b] += wv0[0] * hv[0] + wv0[1] * hv[1] + wv0[2] * hv[2] + wv0[3] * hv[3];
            a1[b] += wv1[0] * hv[0] + wv1[1] * hv[1] + wv1[2] * hv[2] + wv1[3] * hv[3];
        }
    }
#pragma unroll
    for (int b = 0; b < B; ++b) {
#pragma unroll
        for (int mk = 1; mk <= 32; mk <<= 1) {
            a0[b] += __shfl_xor(a0[b], mk);
            a1[b] += __shfl_xor(a1[b], mk);
        }
    }
    if (lane == 0) {
        const float bias0 = bq[j0];
        const float bias1 = bq[j1];
#pragma unroll
        for (int b = 0; b < B; ++b) {
            qout[b * DM + j0] = a0[b] + bias0;
            qout[b * DM + j1] = a1[b] + bias1;
        }
    }
}

// ---------------------------------------------------------------------------
// Kernel 2: flash-decode partial, 4 heads per block -> each wave reads
// 2 KB CONTIGUOUS per row (2x dwordx4 covering 4 head-slices) instead of
// 512 B scattered. Block = (b, head-quad, s-quarter); waves own 64
// consecutive rows. Per-quad softmax in LDS; 4-way combine afterwards.
// ---------------------------------------------------------------------------
__global__ __launch_bounds__(NT) void attn_partial(
    const float* __restrict__ kptr, const float* __restrict__ vptr,
    const float* __restrict__ qws, float* __restrict__ part)
{
    __shared__ float sc[HQ][NR];          // 16 KB
    __shared__ float outp[WAVES][HQ][D];  // 32 KB
    __shared__ float redM[HQ][4];
    __shared__ float redS[HQ][4];

    const int tid  = threadIdx.x;
    const int lane = tid & 63;
    const int w    = tid >> 6;
    const int half = lane >> 5;           // 0/1: which head of the pair
    const int c    = blockIdx.x & (SPLIT - 1);
    const int hq   = (blockIdx.x >> 2) & (NHQ - 1);
    const int b    = blockIdx.x >> 5;

    // float offset of (b, s = c*NR, head hq*4, d=0); row stride DM floats
    const size_t rowbase = ((size_t)b * S + (size_t)c * NR) * DM + hq * (HQ * D);
    const float* kq = kptr + rowbase;
    const float* vq = vptr + rowbase;

    // q fragments: A covers heads hq*4+{0,1}, B covers hq*4+{2,3}
    const v4f qA = *(const v4f*)(qws + (size_t)b * DM + hq * (HQ * D) + 4 * lane);
    const v4f qB = *(const v4f*)(qws + (size_t)b * DM + hq * (HQ * D) + 256 + 4 * lane);

    const int s0 = w * RPW;

    // ---- Phase 1: scores (2 KB contiguous per row per wave) ----
#pragma unroll 4
    for (int i = 0; i < RPW; ++i) {
        const int s = s0 + i;
        const v4f kA = __builtin_nontemporal_load(
            (const v4f*)(kq + (size_t)s * DM + 4 * lane));
        const v4f kB = __builtin_nontemporal_load(
            (const v4f*)(kq + (size_t)s * DM + 256 + 4 * lane));
        float pA = qA[0]*kA[0] + qA[1]*kA[1] + qA[2]*kA[2] + qA[3]*kA[3];
        float pB = qB[0]*kB[0] + qB[1]*kB[1] + qB[2]*kB[2] + qB[3]*kB[3];
#pragma unroll
        for (int mk = 1; mk <= 16; mk <<= 1) {
            pA += __shfl_xor(pA, mk);
            pB += __shfl_xor(pB, mk);
        }
        if ((lane & 31) == 0) {           // lanes 0 and 32
            sc[half][s]     = pA;
            sc[2 + half][s] = pB;
        }
    }
    __syncthreads();

    // ---- per-head softmax over the NR rows (quarter-block per head) ----
    const int qh = tid >> 8;              // head-in-quad 0..3
    const int qt = tid & 255;
    float m = -3.4e38f;
#pragma unroll
    for (int j = 0; j < NR / 256; ++j) m = fmaxf(m, sc[qh][qt + 256 * j]);
#pragma unroll
    for (int mk = 1; mk <= 32; mk <<= 1) m = fmaxf(m, __shfl_xor(m, mk));
    if (lane == 0) redM[qh][w & 3] = m;
    __syncthreads();
    const float M = fmaxf(fmaxf(redM[qh][0], redM[qh][1]),
                          fmaxf(redM[qh][2], redM[qh][3]));
    float lsum = 0.f;
#pragma unroll
    for (int j = 0; j < NR / 256; ++j) {
        const int i = qt + 256 * j;
        const float e = __expf(sc[qh][i] - M);
        sc[qh][i] = e;
        lsum += e;
    }
#pragma unroll
    for (int mk = 1; mk <= 32; mk <<= 1) lsum += __shfl_xor(lsum, mk);
    if (lane == 0) redS[qh][w & 3] = lsum;
    __syncthreads();                      // sc exp-writes + redS visible

    // ---- Phase 2: partial O = exp(S) @ V ----
    v4f accA = {0.f, 0.f, 0.f, 0.f};
    v4f accB = {0.f, 0.f, 0.f, 0.f};
#pragma unroll 4
    for (int i = 0; i < RPW; ++i) {
        const int s = s0 + i;
        const float pA = sc[half][s];         // broadcast per half-wave
        const float pB = sc[2 + half][s];
        const v4f vA = __builtin_nontemporal_load(
            (const v4f*)(vq + (size_t)s * DM + 4 * lane));
        const v4f vB = __builtin_nontemporal_load(
            (const v4f*)(vq + (size_t)s * DM + 256 + 4 * lane));
        accA[0] += pA * vA[0]; accA[1] += pA * vA[1];
        accA[2] += pA * vA[2]; accA[3] += pA * vA[3];
        accB[0] += pB * vB[0]; accB[1] += pB * vB[1];
        accB[2] += pB * vB[2]; accB[3] += pB * vB[3];
    }
    *(v4f*)(&outp[w][half][4 * (lane & 31)])     = accA;
    *(v4f*)(&outp[w][2 + half][4 * (lane & 31)]) = accB;
    __syncthreads();

    // ---- cross-wave reduce + write partial record ----
    if (tid < HQ * D) {
        const int hd = tid >> 7;          // head-in-quad
        const int d  = tid & 127;
        float r = 0.f;
#pragma unroll
        for (int ww = 0; ww < WAVES; ++ww) r += outp[ww][hd][d];
        float* rec = part + ((size_t)(b * H + hq * HQ + hd) * SPLIT + c) * PSTR;
        rec[d] = r;
        if (d == 0) {
            const float Mh = fmaxf(fmaxf(redM[hd][0], redM[hd][1]),
                                   fmaxf(redM[hd][2], redM[hd][3]));
            const float Sh = redS[hd][0] + redS[hd][1] + redS[hd][2] + redS[hd][3];
            rec[D] = Mh;
            rec[D + 1] = Sh;
        }
    }
}

// ---------------------------------------------------------------------------
// Kernel 3: merge the SPLIT partials per (b,h).
// ---------------------------------------------------------------------------
__global__ __launch_bounds__(128) void combine_kernel(
    const float* __restrict__ part, float* __restrict__ out)
{
    const int bh = blockIdx.x;            // 0..255
    const int d  = threadIdx.x;           // 0..127
    const float* rec = part + (size_t)bh * SPLIT * PSTR;

    float M = -3.4e38f;
#pragma unroll
    for (int c = 0; c < SPLIT; ++c) M = fmaxf(M, rec[c * PSTR + D]);
    float denom = 0.f, o = 0.f;
#pragma unroll
    for (int c = 0; c < SPLIT; ++c) {
        const float wgt = __expf(rec[c * PSTR + D] - M);
        denom += wgt * rec[c * PSTR + D + 1];
        o     += wgt * rec[c * PSTR + d];
    }
    out[(size_t)bh * D + d] = o / denom;
}

extern "C" void kernel_launch(void* const* d_in, const int* in_sizes, int n_in,
                              void* d_out, int out_size, void* d_ws, size_t ws_size,
                              hipStream_t stream)
{
    const float* hidden = (const float*)d_in[0];
    const float* keys   = (const float*)d_in[1];
    const float* vals   = (const float*)d_in[2];
    const float* Wq     = (const float*)d_in[3];
    const float* bq     = (const float*)d_in[4];
    float* outp = (float*)d_out;
    float* qws  = (float*)d_ws;                   // B*DM floats = 128 KB
    float* part = qws + (size_t)B * DM;           // 256*4*132 floats ≈ 0.54 MB

    qproj_kernel<<<DM / 8, 256, 0, stream>>>(hidden, Wq, bq, qws);
    attn_partial<<<B * NHQ * SPLIT, NT, 0, stream>>>(keys, vals, qws, part);
    combine_kernel<<<B * H, 128, 0, stream>>>(part, outp);
}